// Round 17
// baseline (373.560 us; speedup 1.0000x reference)
//
#include <hip/hip_runtime.h>
#include <cmath>

#define DIMN 8
#define SSTEPS 2048
#define MZ 64
#define TQN 1024
#define DS_F    4.8828125e-4f           // 1/2048
#define DT_F    1.0e-3f
#define SCALE_F 22.09708691207961f      // sqrt(ds)/dt
#define SQRTDT_F 0.031622776601683794f  // sqrt(dt)
#define LN2_F   0.6931471805599453f

typedef _Float16 f16x8 __attribute__((ext_vector_type(8)));
typedef float f32x4 __attribute__((ext_vector_type(4)));

__device__ __forceinline__ float sigmoidf_(float x) { return 1.f / (1.f + expf(-x)); }

// async global->LDS, 16B/lane; LDS dest = uniform base + lane*16 (wave-uniform base!)
__device__ __forceinline__ void gl_lds16(const _Float16* g, _Float16* l)
{
    __builtin_amdgcn_global_load_lds(
        (const __attribute__((address_space(1))) unsigned int*)g,
        (__attribute__((address_space(3))) unsigned int*)l, 16, 0, 0);
}

// ---------------- coef kernel: hurst -> {e=2h, c=rsqrt(2h ds)/Gamma(h+.5)} at t and t+dt ----
__global__ void coef_kernel(const float* __restrict__ t_in, const float* __restrict__ y0,
                            const float* __restrict__ W1, const float* __restrict__ b1,
                            const float* __restrict__ W2, const float* __restrict__ b2,
                            const float* __restrict__ Wc1, const float* __restrict__ bc1,
                            const float* __restrict__ Wc2, const float* __restrict__ bc2,
                            const float* __restrict__ dw, const float* __restrict__ cw,
                            float4* __restrict__ coef_t, float4* __restrict__ coef_z,
                            float* __restrict__ times_z)
{
    int gid = blockIdx.x * blockDim.x + threadIdx.x;
    if (gid >= TQN + MZ) return;
    bool isz = gid >= TQN;
    float tv;
    if (!isz) {
        tv = t_in[gid];
    } else {
        int j = gid - TQN;
        tv = 0.0055f + (float)j * (0.989f / 63.0f);   // linspace(t0+5.5dt, t1-5.5dt, 64)
        times_z[j] = tv;
    }
    float y = y0[0];
    float hc[10];
    #pragma unroll
    for (int j = 0; j < 10; ++j) hc[j] = tanhf(y * Wc1[j] + bc1[j]);
    float pc[DIMN];
    #pragma unroll
    for (int d = 0; d < DIMN; ++d) {
        float s = bc2[d];
        #pragma unroll
        for (int j = 0; j < 10; ++j) s += hc[j] * Wc2[d * 10 + j];
        pc[d] = sigmoidf_(s);
    }
    float dww = dw[0], cww = cw[0];
    float4 outv[DIMN];
    for (int which = 0; which < 2; ++which) {
        float tt = (which == 0) ? tv : tv + DT_F;
        float st = sinf(tt), ct = cosf(tt);
        float hid[10];
        #pragma unroll
        for (int j = 0; j < 10; ++j)
            hid[j] = tanhf(st * W1[j * 3 + 0] + ct * W1[j * 3 + 1] + tt * W1[j * 3 + 2] + b1[j]);
        #pragma unroll
        for (int d = 0; d < DIMN; ++d) {
            float s = b2[d];
            #pragma unroll
            for (int j = 0; j < 10; ++j) s += hid[j] * W2[d * 10 + j];
            float tc = sigmoidf_(s);
            float h = sigmoidf_(tc * dww + pc[d] * cww);
            float e = 2.f * h;
            float c = rsqrtf(e * DS_F) / tgammaf(h + 0.5f);
            if (which == 0) { outv[d].x = e; outv[d].y = c; }
            else            { outv[d].z = e; outv[d].w = c; }
        }
    }
    float4* dst = isz ? (coef_z + (size_t)(gid - TQN) * DIMN) : (coef_t + (size_t)gid * DIMN);
    #pragma unroll
    for (int d = 0; d < DIMN; ++d) dst[d] = outv[d];
}

// ---------------- bitonic sort of the 1024 t values: tsort / perm / inv --------------------
__global__ __launch_bounds__(512) void sort_kernel(const float* __restrict__ t_in,
                                                   float* __restrict__ tsort,
                                                   int* __restrict__ perm,
                                                   int* __restrict__ inv)
{
    __shared__ float v[1024];
    __shared__ int   ix[1024];
    int tid = threadIdx.x;
    v[tid] = t_in[tid];             ix[tid] = tid;
    v[tid + 512] = t_in[tid + 512]; ix[tid + 512] = tid + 512;
    __syncthreads();
    for (int k = 2; k <= 1024; k <<= 1) {
        for (int j = k >> 1; j > 0; j >>= 1) {
            #pragma unroll 1
            for (int base = 0; base < 1024; base += 512) {
                int i = base + tid;
                int p = i ^ j;
                if (p > i) {                      // owner = lower index; pairs disjoint
                    bool up = ((i & k) == 0);
                    float vi = v[i], vp = v[p];
                    if ((vi > vp) == up) {
                        v[i] = vp; v[p] = vi;
                        int q_ = ix[i]; ix[i] = ix[p]; ix[p] = q_;
                    }
                }
            }
            __syncthreads();
        }
    }
    tsort[tid] = v[tid];           tsort[tid + 512] = v[tid + 512];
    perm[tid] = ix[tid];           perm[tid + 512] = ix[tid + 512];
    inv[ix[tid]] = tid;            inv[ix[tid + 512]] = tid + 512;
}

// ---- strip of 8 weights, difference-form fast math (no catastrophic cancellation) ----------
__device__ __forceinline__ void side_weights(float tt, float e, float c, int sbase,
                                             float (&w)[8])
{
    float xprev = tt - (float)sbase * DS_F;
    float pa = 0.f;
    if (xprev > 0.f) pa = __builtin_amdgcn_exp2f(e * __builtin_amdgcn_logf(xprev));
    #pragma unroll
    for (int k = 1; k <= 8; ++k) {
        float xk = tt - (float)(sbase + k) * DS_F;
        float D, pan;
        if (xk > 0.f) {
            float om = xk * __builtin_amdgcn_rcpf(xprev);     // x_{k+1}/x_k in (0,1)
            float y2 = e * __builtin_amdgcn_logf(om);         // e*log2(om) <= 0
            float wl = y2 * LN2_F;                            // e*ln(om)
            float em = wl * (1.f + wl * (0.5f + wl * (0.16666667f + wl * (0.041666668f + wl * 0.008333334f))));
            float g = -em;
            if (wl < -0.3f) g = 1.f - __builtin_amdgcn_exp2f(y2);
            D = pa * g;
            pan = pa - D;
        } else {
            D = pa;
            pan = 0.f;
        }
        w[k - 1] = __builtin_amdgcn_sqrtf(D + 1e-12f) * c;
        pa = pan;
        xprev = xk;
    }
}

__device__ __forceinline__ unsigned pack_hl(float v)
{
    _Float16 h = (_Float16)v;
    _Float16 l = (_Float16)(v - (float)h);
    unsigned short hu = __builtin_bit_cast(unsigned short, h);
    unsigned short lu = __builtin_bit_cast(unsigned short, l);
    return (unsigned)hu | ((unsigned)lu << 16);
}

// ---------------- kmat_t: K(t) SORTED rows -> fp16 hi/lo split, [d][t_sorted][s] -----------
__global__ __launch_bounds__(256) void kmat_t_kernel(const float* __restrict__ tsort,
                                                     const int* __restrict__ perm,
                                                     const float4* __restrict__ coef,
                                                     _Float16* __restrict__ KThi,
                                                     _Float16* __restrict__ KTlo)
{
    int band = blockIdx.x >> 2;
    float bmax = tsort[band * 128 + 127];
    if ((float)(blockIdx.y * 64) * DS_F > bmax + DT_F + 0.07f) return;  // block-uniform
    int tid = threadIdx.x;
    int txx = tid & 31, sidx = tid >> 5;
    int t = blockIdx.x * 32 + txx;
    int sbase = blockIdx.y * 64 + sidx * 8;
    int d = blockIdx.z;
    __shared__ unsigned shhl[32][65];
    float tq = tsort[t];
    float4 cf = coef[(size_t)perm[t] * DIMN + d];
    float wa[8], wb[8];
    side_weights(tq,        cf.x, cf.y, sbase, wa);
    side_weights(tq + DT_F, cf.z, cf.w, sbase, wb);
    #pragma unroll
    for (int k = 0; k < 8; ++k) {
        float v = fmaxf(wb[k] - wa[k], 0.f) * SCALE_F;
        shhl[txx][sidx * 8 + k] = pack_hl(v);
    }
    __syncthreads();
    int tl = tid >> 3, sc = tid & 7;
    unsigned dwv[8];
    #pragma unroll
    for (int j = 0; j < 8; ++j) dwv[j] = shhl[tl][sc * 8 + j];
    uint4 hv, lv;
    hv.x = __builtin_amdgcn_perm(dwv[1], dwv[0], 0x05040100u);
    hv.y = __builtin_amdgcn_perm(dwv[3], dwv[2], 0x05040100u);
    hv.z = __builtin_amdgcn_perm(dwv[5], dwv[4], 0x05040100u);
    hv.w = __builtin_amdgcn_perm(dwv[7], dwv[6], 0x05040100u);
    lv.x = __builtin_amdgcn_perm(dwv[1], dwv[0], 0x07060302u);
    lv.y = __builtin_amdgcn_perm(dwv[3], dwv[2], 0x07060302u);
    lv.z = __builtin_amdgcn_perm(dwv[5], dwv[4], 0x07060302u);
    lv.w = __builtin_amdgcn_perm(dwv[7], dwv[6], 0x07060302u);
    size_t o = ((size_t)(d * 1024) + blockIdx.x * 32 + tl) * 2048 + blockIdx.y * 64 + sc * 8;
    *(uint4*)&KThi[o] = hv;
    *(uint4*)&KTlo[o] = lv;
}

// ---------------- kmat_z: fp32 [d][s][m] AND fp16 split transposed [d][m][s] ---------------
__global__ __launch_bounds__(256) void kmat_z_kernel(const float* __restrict__ times,
                                                     const float4* __restrict__ coef,
                                                     float* __restrict__ Kz,
                                                     _Float16* __restrict__ KzThi,
                                                     _Float16* __restrict__ KzTlo)
{
    int tid = threadIdx.x;
    int txx = tid & 31, sidx = tid >> 5;
    int m = blockIdx.x * 32 + txx;
    int sbase = blockIdx.y * 64 + sidx * 8;
    int d = blockIdx.z;
    __shared__ unsigned shhl[32][65];
    float tq = times[m];
    float4 cf = coef[(size_t)m * DIMN + d];
    float wa[8], wb[8];
    side_weights(tq,        cf.x, cf.y, sbase, wa);
    side_weights(tq + DT_F, cf.z, cf.w, sbase, wb);
    #pragma unroll
    for (int k = 0; k < 8; ++k) {
        float v = fmaxf(wb[k] - wa[k], 0.f) * SCALE_F;
        Kz[((size_t)d * SSTEPS + sbase + k) * 64 + m] = v;
        shhl[txx][sidx * 8 + k] = pack_hl(v);
    }
    __syncthreads();
    int tl = tid >> 3, sc = tid & 7;
    unsigned dwv[8];
    #pragma unroll
    for (int j = 0; j < 8; ++j) dwv[j] = shhl[tl][sc * 8 + j];
    uint4 hv, lv;
    hv.x = __builtin_amdgcn_perm(dwv[1], dwv[0], 0x05040100u);
    hv.y = __builtin_amdgcn_perm(dwv[3], dwv[2], 0x05040100u);
    hv.z = __builtin_amdgcn_perm(dwv[5], dwv[4], 0x05040100u);
    hv.w = __builtin_amdgcn_perm(dwv[7], dwv[6], 0x05040100u);
    lv.x = __builtin_amdgcn_perm(dwv[1], dwv[0], 0x07060302u);
    lv.y = __builtin_amdgcn_perm(dwv[3], dwv[2], 0x07060302u);
    lv.z = __builtin_amdgcn_perm(dwv[5], dwv[4], 0x07060302u);
    lv.w = __builtin_amdgcn_perm(dwv[7], dwv[6], 0x07060302u);
    size_t o = ((size_t)(d * 64) + blockIdx.x * 32 + tl) * 2048 + blockIdx.y * 64 + sc * 8;
    *(uint4*)&KzThi[o] = hv;
    *(uint4*)&KzTlo[o] = lv;
}

// ---------------- Kzz partials: Kz^T Kz per dim, k-split 8 ---------------------------------
__global__ __launch_bounds__(256) void kzz_partial_kernel(const float* __restrict__ Kz,
                                                          float* __restrict__ part)
{
    int kidx = blockIdx.x;           // 0..7 (256 s each)
    int d = blockIdx.y;
    int tid = threadIdx.x, tx = tid & 15, ty = tid >> 4;
    __shared__ float As[32][64];
    float acc[4][4] = {};
    const float* base = Kz + ((size_t)d * SSTEPS + (size_t)kidx * 256) * 64;
    for (int c = 0; c < 8; ++c) {
        __syncthreads();
        #pragma unroll
        for (int l = 0; l < 2; ++l) {
            int idx = tid + l * 256;               // 512 float4
            int r = idx >> 4, c4 = idx & 15;
            *(float4*)&As[r][c4 * 4] = *(const float4*)(base + (size_t)(c * 32 + r) * 64 + c4 * 4);
        }
        __syncthreads();
        #pragma unroll
        for (int k = 0; k < 32; ++k) {
            float av[4], bv[4];
            *(float4*)&av[0] = *(float4*)&As[k][ty * 4];
            *(float4*)&bv[0] = *(float4*)&As[k][tx * 4];
            #pragma unroll
            for (int i = 0; i < 4; ++i)
                #pragma unroll
                for (int j = 0; j < 4; ++j) acc[i][j] += av[i] * bv[j];
        }
    }
    float* dst = part + (size_t)(kidx * DIMN + d) * 4096;
    #pragma unroll
    for (int i = 0; i < 4; ++i)
        *(float4*)&dst[(size_t)(ty * 4 + i) * 64 + tx * 4] =
            make_float4(acc[i][0], acc[i][1], acc[i][2], acc[i][3]);
}

// ---------------- Cholesky: 256-thread fused reduce + factorization + delta_Bz -------------
// R17 (= R12-validated pattern): parallel coalesced 8-way partial sum (256 thr x 16 entries)
// replaces the separate reduce_kernel dispatch. Factorization runs redundantly on all 4
// waves (same-value LDS writes, barrier-ordered -> deterministic); global writes on tid<64.
__global__ __launch_bounds__(256) void chol_kernel(const float* __restrict__ part1,
                                                   const float* __restrict__ eps_z,
                                                   float* __restrict__ Lz, float* __restrict__ dBz)
{
    int d = blockIdx.x, tid = threadIdx.x;
    int i = tid & 63;
    __shared__ float A[64][65];
    for (int e = tid; e < 4096; e += 256) {
        int r = e >> 6, c = e & 63;
        float s = 0.f;
        #pragma unroll
        for (int p = 0; p < 8; ++p) s += part1[(size_t)p * 32768 + (size_t)d * 4096 + e];
        A[r][c] = s + ((r == c) ? 1e-6f : 0.f);
    }
    __syncthreads();
    for (int j = 0; j < 64; ++j) {
        float s = 0.f;
        if (i >= j) {
            float s0 = 0.f, s1 = 0.f, s2 = 0.f, s3 = 0.f;
            int k = 0;
            for (; k + 4 <= j; k += 4) {
                s0 += A[i][k]     * A[j][k];
                s1 += A[i][k + 1] * A[j][k + 1];
                s2 += A[i][k + 2] * A[j][k + 2];
                s3 += A[i][k + 3] * A[j][k + 3];
            }
            for (; k < j; ++k) s0 += A[i][k] * A[j][k];
            s = A[i][j] - ((s0 + s1) + (s2 + s3));
        }
        __syncthreads();
        if (i == j) A[j][j] = sqrtf(fmaxf(s, 1e-30f));   // 4 waves, identical value
        __syncthreads();
        if (i > j) A[i][j] = s / A[j][j];                // 4 waves, identical value
        __syncthreads();
    }
    if (tid < 64) {
        for (int r = 0; r < 64; ++r)
            Lz[(size_t)d * 4096 + (size_t)r * 64 + i] = (i <= r) ? A[r][i] : 0.f;
        float s0 = 0.f, s1 = 0.f, s2 = 0.f, s3 = 0.f;
        int k = 0;
        for (; k + 4 <= i + 1; k += 4) {
            s0 += A[i][k]     * eps_z[d * 64 + k];
            s1 += A[i][k + 1] * eps_z[d * 64 + k + 1];
            s2 += A[i][k + 2] * eps_z[d * 64 + k + 2];
            s3 += A[i][k + 3] * eps_z[d * 64 + k + 3];
        }
        for (; k <= i; ++k) s0 += A[i][k] * eps_z[d * 64 + k];
        dBz[d * 64 + i] = (s0 + s1) + (s2 + s3);
    }
}

// ---------------- Ktz partials via MFMA; sorted-t support clamp ----------------------------
__global__ __launch_bounds__(256, 2) void ktz_mfma_kernel(const _Float16* __restrict__ KThi,
                                                          const _Float16* __restrict__ KTlo,
                                                          const _Float16* __restrict__ KzThi,
                                                          const _Float16* __restrict__ KzTlo,
                                                          const float* __restrict__ tsort,
                                                          float* __restrict__ part)
{
    int tid = threadIdx.x;
    int wave = tid >> 6, lane = tid & 63;
    int n = lane & 15, q = lane >> 4;
    int lr = lane >> 2, lc = (lane & 3) * 8;
    int d = blockIdx.x;                 // fastest -> XCD locality
    int t0 = blockIdx.y * 128;
    int split = blockIdx.z;
    int wr = (wave >> 1) * 64, wc = (wave & 1) * 32;

    float tmax = tsort[t0 + 127];
    int klim = (int)floorf((tmax + DT_F) * 64.f) + 2;   // global 32-step chunk limit
    int nc = klim - split * 16;
    nc = nc < 0 ? 0 : (nc > 16 ? 16 : nc);

    __shared__ _Float16 Ah[2][128][32], Al[2][128][32];
    __shared__ _Float16 Bh[2][64][32],  Bl[2][64][32];   // 48 KB

    f32x4 acc[4][2];
    #pragma unroll
    for (int i = 0; i < 4; ++i)
        #pragma unroll
        for (int j = 0; j < 2; ++j) acc[i][j] = (f32x4)0.f;

    const size_t aRow = (size_t)(d * 1024 + t0);
    const size_t bRow = (size_t)(d * 64);
    int segA = wave * 32;               // 32 A rows per wave (2 instrs)
    int segB = wave * 16;               // 16 B rows per wave (1 instr)

    auto stage = [&](int buf, int c) {
        int s0 = split * 512 + c * 32;
        size_t ga = (aRow + segA + lr) * 2048 + s0 + lc;
        size_t gb = (bRow + segB + lr) * 2048 + s0 + lc;
        gl_lds16(KThi + ga,               &Ah[buf][segA][0]);
        gl_lds16(KThi + ga + 16 * 2048,   &Ah[buf][segA + 16][0]);
        gl_lds16(KTlo + ga,               &Al[buf][segA][0]);
        gl_lds16(KTlo + ga + 16 * 2048,   &Al[buf][segA + 16][0]);
        gl_lds16(KzThi + gb,              &Bh[buf][segB][0]);
        gl_lds16(KzTlo + gb,              &Bl[buf][segB][0]);
    };

    if (nc > 0) stage(0, 0);            // 6 DMA per wave
    for (int c = 0; c < nc; ++c) {
        int buf = c & 1;
        asm volatile("s_waitcnt vmcnt(0)" ::: "memory");
        __builtin_amdgcn_s_barrier();
        __builtin_amdgcn_sched_barrier(0);
        if (c + 1 < nc) stage(buf ^ 1, c + 1);   // overwrites buf read at c-1: drained
        f16x8 fAh[4], fAl[4], fBh[2], fBl[2];
        #pragma unroll
        for (int i = 0; i < 4; ++i) {
            fAh[i] = *(f16x8*)&Ah[buf][wr + i * 16 + n][q * 8];
            fAl[i] = *(f16x8*)&Al[buf][wr + i * 16 + n][q * 8];
        }
        #pragma unroll
        for (int j = 0; j < 2; ++j) {
            fBh[j] = *(f16x8*)&Bh[buf][wc + j * 16 + n][q * 8];
            fBl[j] = *(f16x8*)&Bl[buf][wc + j * 16 + n][q * 8];
        }
        __builtin_amdgcn_s_setprio(1);
        #pragma unroll
        for (int i = 0; i < 4; ++i)
            #pragma unroll
            for (int j = 0; j < 2; ++j) {
                acc[i][j] = __builtin_amdgcn_mfma_f32_16x16x32_f16(fAh[i], fBh[j], acc[i][j], 0, 0, 0);
                acc[i][j] = __builtin_amdgcn_mfma_f32_16x16x32_f16(fAh[i], fBl[j], acc[i][j], 0, 0, 0);
                acc[i][j] = __builtin_amdgcn_mfma_f32_16x16x32_f16(fAl[i], fBh[j], acc[i][j], 0, 0, 0);
            }
        __builtin_amdgcn_s_setprio(0);
    }
    float* dst = part + ((size_t)(split * DIMN + d)) * 1024 * 64;
    #pragma unroll
    for (int i = 0; i < 4; ++i)
        #pragma unroll
        for (int j = 0; j < 2; ++j)
            #pragma unroll
            for (int r = 0; r < 4; ++r) {
                int t = t0 + wr + i * 16 + q * 4 + r;
                dst[(size_t)t * 64 + wc + j * 16 + n] = acc[i][j][r];
            }
}

// ------ fused: sum Ktz partials + cho_solve + alpha splits + mean (perm-scattered) ---------
// R16-validated: B column staged through LDS (bLs[i][r], coalesced) then x[k] = bLs[k][i]
// -> register-resident solve with float4-broadcast L/LT rows.
__global__ __launch_bounds__(64) void solve_kernel(const float* __restrict__ Lz,
                                                   const float* __restrict__ part2,
                                                   const float* __restrict__ dBz,
                                                   const int* __restrict__ perm,
                                                   _Float16* __restrict__ aPhi,
                                                   _Float16* __restrict__ aPlo,
                                                   _Float16* __restrict__ aNhi,
                                                   _Float16* __restrict__ aNlo,
                                                   float* __restrict__ out0)
{
    int d = blockIdx.y;
    int t0 = blockIdx.x * 64;
    int i = threadIdx.x;
    __shared__ float L[64][68];       // row-major, padded: float4 at k%4==0 is 16B-aligned
    __shared__ float LT[64][68];      // LT[j][k] = L[k][j] for backward pass
    __shared__ float bLs[64][65];     // transpose staging: bLs[m][c] = B[t0+c][m]
    __shared__ float inv[64];
    __shared__ float dB[64];
    for (int r = 0; r < 64; ++r) {
        float v = Lz[(size_t)d * 4096 + (size_t)r * 64 + i];
        L[r][i] = v;
        LT[i][r] = v;
    }
    dB[i] = dBz[d * 64 + i];
    // coalesced global load (lane = m), transposed into LDS: bLs[i][r] = B[t0+r][m=i]
    for (int r = 0; r < 64; ++r) {
        size_t base = ((size_t)d * 1024 + t0 + r) * 64 + i;
        bLs[i][r] = (part2[base] + part2[base + 524288]) +
                    (part2[base + 1048576] + part2[base + 1572864]);
    }
    __syncthreads();
    inv[i] = 1.f / L[i][i];
    __syncthreads();
    // thread i's RHS column: x[k] = B[t0+i][m=k]  (row-k read, lane-stride-1, conflict-free)
    float x[64];
    #pragma unroll
    for (int k = 0; k < 64; ++k) x[k] = bLs[k][i];
    // forward: x[j] = (x[j] - sum_{k<j} L[j][k] x[k]) / L[j][j]; L rows via float4 broadcast
    #pragma unroll
    for (int j = 0; j < 64; ++j) {
        float s0 = 0.f, s1 = 0.f, s2 = 0.f, s3 = 0.f;
        #pragma unroll
        for (int k = 0; k + 4 <= j; k += 4) {
            float4 lv = *(const float4*)&L[j][k];
            s0 += lv.x * x[k];     s1 += lv.y * x[k + 1];
            s2 += lv.z * x[k + 2]; s3 += lv.w * x[k + 3];
        }
        #pragma unroll
        for (int k = j & ~3; k < j; ++k) s0 += L[j][k] * x[k];
        x[j] = (x[j] - ((s0 + s1) + (s2 + s3))) * inv[j];
    }
    // backward: x[j] = (x[j] - sum_{k>j} L[k][j] x[k]) / L[j][j]; LT rows via float4
    #pragma unroll
    for (int j = 63; j >= 0; --j) {
        float s0 = 0.f, s1 = 0.f, s2 = 0.f, s3 = 0.f;
        #pragma unroll
        for (int k = j + 1; k < ((j + 4) & ~3); ++k) s0 += LT[j][k] * x[k];   // head
        #pragma unroll
        for (int k = (j + 4) & ~3; k + 4 <= 64; k += 4) {
            float4 lv = *(const float4*)&LT[j][k];
            s0 += lv.x * x[k];     s1 += lv.y * x[k + 1];
            s2 += lv.z * x[k + 2]; s3 += lv.w * x[k + 3];
        }
        x[j] = (x[j] - ((s0 + s1) + (s2 + s3))) * inv[j];
    }
    // mean = dot(x, dB) -> scatter to ORIGINAL t index
    {
        float m0 = 0.f, m1 = 0.f, m2 = 0.f, m3 = 0.f;
        #pragma unroll
        for (int m = 0; m < 64; m += 4) {
            m0 += x[m]     * dB[m];
            m1 += x[m + 1] * dB[m + 1];
            m2 += x[m + 2] * dB[m + 2];
            m3 += x[m + 3] * dB[m + 3];
        }
        out0[d * 1024 + perm[t0 + i]] = (m0 + m1) + (m2 + m3);
    }
    // emit fp16 hi/lo splits, [d][t_sorted][m], +/- variants (all static indices)
    size_t o = ((size_t)(d * 1024 + t0 + i)) * 64;
    #pragma unroll
    for (int g = 0; g < 8; ++g) {
        union { _Float16 h[8]; float4 v; } ph, pl, nh, nl;
        #pragma unroll
        for (int k = 0; k < 8; ++k) {
            float xv = x[g * 8 + k];
            _Float16 h = (_Float16)xv;
            _Float16 lo = (_Float16)(xv - (float)h);
            ph.h[k] = h;  pl.h[k] = lo;
            nh.h[k] = -h; nl.h[k] = -lo;
        }
        *(float4*)&aPhi[o + g * 8] = ph.v;
        *(float4*)&aPlo[o + g * 8] = pl.v;
        *(float4*)&aNhi[o + g * 8] = nh.v;
        *(float4*)&aNlo[o + g * 8] = nl.v;
    }
}

// ---------------- var/std via MFMA: R7 structure + sorted-support chunk clamp --------------
__global__ __launch_bounds__(256, 3) void var_mfma_kernel(const _Float16* __restrict__ KThi,
                                                          const _Float16* __restrict__ KTlo,
                                                          const _Float16* __restrict__ aPhi,
                                                          const _Float16* __restrict__ aPlo,
                                                          const _Float16* __restrict__ aNhi,
                                                          const _Float16* __restrict__ aNlo,
                                                          const float* __restrict__ tsort,
                                                          const int* __restrict__ perm,
                                                          float* __restrict__ out1)
{
    int tid = threadIdx.x;
    int wave = tid >> 6, lane = tid & 63;
    int n = lane & 15, q = lane >> 4;
    int lr = lane >> 2;
    int lcs = (((lane & 3) ^ ((lr >> 1) & 3)) * 8);   // swizzled DMA source col (f16 units)
    int qs  = ((q ^ ((n >> 1) & 3)) * 8);             // swizzled LDS read col (f16 units)
    int d = blockIdx.x;                               // fastest -> XCD locality
    // decode triangle tile: per t-band ti (128 rows), u-tiles uj in [2*ti, 16)
    int ti = 0, rem = blockIdx.y;
    while (rem >= 16 - 2 * ti) { rem -= 16 - 2 * ti; ++ti; }
    int uj = 2 * ti + rem;
    int t0 = ti * 128, u0 = uj * 64;
    int wr = (wave >> 1) * 64, wc = (wave & 1) * 32;  // wave's 64(t) x 32(u) quadrant

    float tmaxv = tsort[t0 + 127];
    float umaxv = tsort[u0 + 63];
    int nck = (int)floorf((fminf(tmaxv, umaxv) + DT_F) * 64.f) + 2;
    if (nck > 64) nck = 64;
    int nit = nck + 2;                                // + alpha chunks {64,65}

    __shared__ _Float16 Ah[2][128][32], Al[2][128][32];   // 16 KB each
    __shared__ _Float16 Bh[2][64][32],  Bl[2][64][32];    // 8 KB each -> 48 KB total

    f32x4 acc[4][2];
    #pragma unroll
    for (int i = 0; i < 4; ++i)
        #pragma unroll
        for (int j = 0; j < 2; ++j) acc[i][j] = (f32x4)0.f;

    const size_t aRow = (size_t)(d * 1024 + t0);
    const size_t bRow = (size_t)(d * 1024 + u0);
    int sa = wave * 32;                 // A rows staged by this wave (2 instrs/plane)
    int sb = wave * 16;                 // B rows staged by this wave (1 instr/plane)

    auto stage = [&](int buf, int ck) {
        const _Float16 *ph, *pl, *qh, *ql;
        size_t str; int col;
        if (ck < 64) { ph = KThi; pl = KTlo; qh = KThi; ql = KTlo; str = 2048; col = ck * 32; }
        else         { ph = aPhi; pl = aPlo; qh = aNhi; ql = aNlo; str = 64;  col = (ck - 64) * 32; }
        size_t ga = (aRow + sa + lr) * str + col + lcs;
        size_t gb = (bRow + sb + lr) * str + col + lcs;
        gl_lds16(ph + ga,            &Ah[buf][sa][0]);
        gl_lds16(ph + ga + 16 * str, &Ah[buf][sa + 16][0]);
        gl_lds16(pl + ga,            &Al[buf][sa][0]);
        gl_lds16(pl + ga + 16 * str, &Al[buf][sa + 16][0]);
        gl_lds16(qh + gb,            &Bh[buf][sb][0]);
        gl_lds16(ql + gb,            &Bl[buf][sb][0]);
    };

    stage(0, 0);                         // 6 DMA per wave (nck >= 5 always: t >= 0.05)
    for (int it = 0; it < nit; ++it) {
        int buf = it & 1;
        asm volatile("s_waitcnt vmcnt(0)" ::: "memory");
        __builtin_amdgcn_s_barrier();
        __builtin_amdgcn_sched_barrier(0);
        int nx = it + 1;
        if (nx < nit) stage(buf ^ 1, nx < nck ? nx : 64 + (nx - nck));
        f16x8 fAh[4], fAl[4], fBh[2], fBl[2];
        #pragma unroll
        for (int i = 0; i < 4; ++i) {
            fAh[i] = *(f16x8*)&Ah[buf][wr + i * 16 + n][qs];
            fAl[i] = *(f16x8*)&Al[buf][wr + i * 16 + n][qs];
        }
        #pragma unroll
        for (int j = 0; j < 2; ++j) {
            fBh[j] = *(f16x8*)&Bh[buf][wc + j * 16 + n][qs];
            fBl[j] = *(f16x8*)&Bl[buf][wc + j * 16 + n][qs];
        }
        __builtin_amdgcn_s_setprio(1);
        #pragma unroll
        for (int i = 0; i < 4; ++i)
            #pragma unroll
            for (int j = 0; j < 2; ++j) {
                acc[i][j] = __builtin_amdgcn_mfma_f32_16x16x32_f16(fAh[i], fBh[j], acc[i][j], 0, 0, 0);
                acc[i][j] = __builtin_amdgcn_mfma_f32_16x16x32_f16(fAh[i], fBl[j], acc[i][j], 0, 0, 0);
                acc[i][j] = __builtin_amdgcn_mfma_f32_16x16x32_f16(fAl[i], fBh[j], acc[i][j], 0, 0, 0);
            }
        __builtin_amdgcn_s_setprio(0);
    }
    float* dst = out1 + ((size_t)d << 20);
    int tw0 = t0 + wr;                       // wave's first sorted t
    int uw0 = u0 + wc;                       // wave's first sorted u
    bool above = (uw0 >= tw0 + 64);          // whole wave strictly u > t (sorted idx)
    bool below = (uw0 + 32 <= tw0);          // whole wave strictly u < t (mirror elsewhere)
    if (!below) {
        #pragma unroll
        for (int i = 0; i < 4; ++i) {
            int tb = tw0 + i * 16 + q * 4;   // sorted t base for r=0..3
            #pragma unroll
            for (int j = 0; j < 2; ++j) {
                int u = uw0 + j * 16 + n;
                int pu = perm[u];
                float fv[4];
                #pragma unroll
                for (int r = 0; r < 4; ++r)
                    fv[r] = sqrtf(fmaxf(acc[i][j][r], 1e-12f)) * SQRTDT_F;
                if (above) {
                    #pragma unroll
                    for (int r = 0; r < 4; ++r)
                        dst[(size_t)perm[tb + r] * 1024 + u] = fv[r];
                    // mirror: final row pu, sorted cols tb..tb+3 contiguous -> coalesced
                    *(float4*)&dst[(size_t)pu * 1024 + tb] = make_float4(fv[0], fv[1], fv[2], fv[3]);
                } else {
                    #pragma unroll
                    for (int r = 0; r < 4; ++r) {
                        int t = tb + r;
                        if (u >= t) dst[(size_t)perm[t] * 1024 + u] = fv[r];
                        if (u > t)  dst[(size_t)pu * 1024 + t] = fv[r];
                    }
                }
            }
        }
    }
}

// ---------------- in-place column un-permutation of out1 (rows already final) --------------
__global__ __launch_bounds__(256) void colperm_kernel(float* __restrict__ out1,
                                                      const int* __restrict__ invp)
{
    int d = blockIdx.y, row = blockIdx.x;
    float* rp = out1 + ((size_t)d << 20) + (size_t)row * 1024;
    __shared__ float buf[1024];
    int tid = threadIdx.x;
    *(float4*)&buf[tid * 4] = *(float4*)&rp[tid * 4];
    __syncthreads();
    #pragma unroll
    for (int k = 0; k < 4; ++k) {
        int b = tid + k * 256;
        rp[b] = buf[invp[b]];
    }
}

extern "C" void kernel_launch(void* const* d_in, const int* in_sizes, int n_in,
                              void* d_out, int out_size, void* d_ws, size_t ws_size,
                              hipStream_t stream)
{
    const float* t_in  = (const float*)d_in[0];
    const float* y0    = (const float*)d_in[1];
    const float* eps_z = (const float*)d_in[2];
    const float* W1    = (const float*)d_in[3];
    const float* b1    = (const float*)d_in[4];
    const float* W2    = (const float*)d_in[5];
    const float* b2    = (const float*)d_in[6];
    const float* Wc1   = (const float*)d_in[7];
    const float* bc1   = (const float*)d_in[8];
    const float* Wc2   = (const float*)d_in[9];
    const float* bc2   = (const float*)d_in[10];
    const float* dw    = (const float*)d_in[11];
    const float* cw    = (const float*)d_in[12];

    float* ws = (float*)d_ws;
    size_t off = 0;
    auto carve = [&](size_t n) { float* p = ws + off; off += n; return p; };
    float* coef_t   = carve(32768);
    float* coef_z   = carve(2048);
    float* times_z  = carve(64);
    float* Kzz      = carve(32768);   // kept for workspace-layout stability (unused)
    float* Lz       = carve(32768);
    float* dBz      = carve(512);
    float* Kz       = carve(1048576);
    _Float16* KThi  = (_Float16*)carve(8388608);
    _Float16* KTlo  = (_Float16*)carve(8388608);
    _Float16* KzThi = (_Float16*)carve(524288);
    _Float16* KzTlo = (_Float16*)carve(524288);
    float* part1    = carve(262144);
    float* part2    = carve(2097152);
    _Float16* aPhi  = (_Float16*)carve(262144);
    _Float16* aPlo  = (_Float16*)carve(262144);
    _Float16* aNhi  = (_Float16*)carve(262144);
    _Float16* aNlo  = (_Float16*)carve(262144);
    float* tsort    = carve(1024);
    int*   perm_i   = (int*)carve(1024);
    int*   inv_i    = (int*)carve(1024);
    (void)Kzz;

    float* out0 = (float*)d_out;
    float* out1 = out0 + (size_t)DIMN * 1024;

    coef_kernel<<<9, 128, 0, stream>>>(t_in, y0, W1, b1, W2, b2, Wc1, bc1, Wc2, bc2, dw, cw,
                                       (float4*)coef_t, (float4*)coef_z, times_z);
    sort_kernel<<<1, 512, 0, stream>>>(t_in, tsort, perm_i, inv_i);
    kmat_t_kernel<<<dim3(32, 32, 8), 256, 0, stream>>>(tsort, perm_i, (const float4*)coef_t,
                                                       KThi, KTlo);
    kmat_z_kernel<<<dim3(2, 32, 8), 256, 0, stream>>>(times_z, (const float4*)coef_z,
                                                      Kz, KzThi, KzTlo);
    kzz_partial_kernel<<<dim3(8, 8), 256, 0, stream>>>(Kz, part1);
    chol_kernel<<<8, 256, 0, stream>>>(part1, eps_z, Lz, dBz);
    ktz_mfma_kernel<<<dim3(8, 8, 4), 256, 0, stream>>>(KThi, KTlo, KzThi, KzTlo, tsort, part2);
    solve_kernel<<<dim3(16, 8), 64, 0, stream>>>(Lz, part2, dBz, perm_i,
                                                 aPhi, aPlo, aNhi, aNlo, out0);
    var_mfma_kernel<<<dim3(8, 72), 256, 0, stream>>>(KThi, KTlo, aPhi, aPlo, aNhi, aNlo,
                                                     tsort, perm_i, out1);
    colperm_kernel<<<dim3(1024, 8), 256, 0, stream>>>(out1, inv_i);
}

// Round 18
// 340.692 us; speedup vs baseline: 1.0965x; 1.0965x over previous
//
#include <hip/hip_runtime.h>
#include <cmath>

#define DIMN 8
#define SSTEPS 2048
#define MZ 64
#define TQN 1024
#define DS_F    4.8828125e-4f           // 1/2048
#define DT_F    1.0e-3f
#define SCALE_F 22.09708691207961f      // sqrt(ds)/dt
#define SQRTDT_F 0.031622776601683794f  // sqrt(dt)
#define LN2_F   0.6931471805599453f

typedef _Float16 f16x8 __attribute__((ext_vector_type(8)));
typedef float f32x4 __attribute__((ext_vector_type(4)));

__device__ __forceinline__ float sigmoidf_(float x) { return 1.f / (1.f + expf(-x)); }

// async global->LDS, 16B/lane; LDS dest = uniform base + lane*16 (wave-uniform base!)
__device__ __forceinline__ void gl_lds16(const _Float16* g, _Float16* l)
{
    __builtin_amdgcn_global_load_lds(
        (const __attribute__((address_space(1))) unsigned int*)g,
        (__attribute__((address_space(3))) unsigned int*)l, 16, 0, 0);
}

// ---------------- coef kernel: hurst -> {e=2h, c=rsqrt(2h ds)/Gamma(h+.5)} at t and t+dt ----
__global__ void coef_kernel(const float* __restrict__ t_in, const float* __restrict__ y0,
                            const float* __restrict__ W1, const float* __restrict__ b1,
                            const float* __restrict__ W2, const float* __restrict__ b2,
                            const float* __restrict__ Wc1, const float* __restrict__ bc1,
                            const float* __restrict__ Wc2, const float* __restrict__ bc2,
                            const float* __restrict__ dw, const float* __restrict__ cw,
                            float4* __restrict__ coef_t, float4* __restrict__ coef_z,
                            float* __restrict__ times_z)
{
    int gid = blockIdx.x * blockDim.x + threadIdx.x;
    if (gid >= TQN + MZ) return;
    bool isz = gid >= TQN;
    float tv;
    if (!isz) {
        tv = t_in[gid];
    } else {
        int j = gid - TQN;
        tv = 0.0055f + (float)j * (0.989f / 63.0f);   // linspace(t0+5.5dt, t1-5.5dt, 64)
        times_z[j] = tv;
    }
    float y = y0[0];
    float hc[10];
    #pragma unroll
    for (int j = 0; j < 10; ++j) hc[j] = tanhf(y * Wc1[j] + bc1[j]);
    float pc[DIMN];
    #pragma unroll
    for (int d = 0; d < DIMN; ++d) {
        float s = bc2[d];
        #pragma unroll
        for (int j = 0; j < 10; ++j) s += hc[j] * Wc2[d * 10 + j];
        pc[d] = sigmoidf_(s);
    }
    float dww = dw[0], cww = cw[0];
    float4 outv[DIMN];
    for (int which = 0; which < 2; ++which) {
        float tt = (which == 0) ? tv : tv + DT_F;
        float st = sinf(tt), ct = cosf(tt);
        float hid[10];
        #pragma unroll
        for (int j = 0; j < 10; ++j)
            hid[j] = tanhf(st * W1[j * 3 + 0] + ct * W1[j * 3 + 1] + tt * W1[j * 3 + 2] + b1[j]);
        #pragma unroll
        for (int d = 0; d < DIMN; ++d) {
            float s = b2[d];
            #pragma unroll
            for (int j = 0; j < 10; ++j) s += hid[j] * W2[d * 10 + j];
            float tc = sigmoidf_(s);
            float h = sigmoidf_(tc * dww + pc[d] * cww);
            float e = 2.f * h;
            float c = rsqrtf(e * DS_F) / tgammaf(h + 0.5f);
            if (which == 0) { outv[d].x = e; outv[d].y = c; }
            else            { outv[d].z = e; outv[d].w = c; }
        }
    }
    float4* dst = isz ? (coef_z + (size_t)(gid - TQN) * DIMN) : (coef_t + (size_t)gid * DIMN);
    #pragma unroll
    for (int d = 0; d < DIMN; ++d) dst[d] = outv[d];
}

// ---------------- bitonic sort of the 1024 t values: tsort / perm / inv --------------------
__global__ __launch_bounds__(512) void sort_kernel(const float* __restrict__ t_in,
                                                   float* __restrict__ tsort,
                                                   int* __restrict__ perm,
                                                   int* __restrict__ inv)
{
    __shared__ float v[1024];
    __shared__ int   ix[1024];
    int tid = threadIdx.x;
    v[tid] = t_in[tid];             ix[tid] = tid;
    v[tid + 512] = t_in[tid + 512]; ix[tid + 512] = tid + 512;
    __syncthreads();
    for (int k = 2; k <= 1024; k <<= 1) {
        for (int j = k >> 1; j > 0; j >>= 1) {
            #pragma unroll 1
            for (int base = 0; base < 1024; base += 512) {
                int i = base + tid;
                int p = i ^ j;
                if (p > i) {                      // owner = lower index; pairs disjoint
                    bool up = ((i & k) == 0);
                    float vi = v[i], vp = v[p];
                    if ((vi > vp) == up) {
                        v[i] = vp; v[p] = vi;
                        int q_ = ix[i]; ix[i] = ix[p]; ix[p] = q_;
                    }
                }
            }
            __syncthreads();
        }
    }
    tsort[tid] = v[tid];           tsort[tid + 512] = v[tid + 512];
    perm[tid] = ix[tid];           perm[tid + 512] = ix[tid + 512];
    inv[ix[tid]] = tid;            inv[ix[tid + 512]] = tid + 512;
}

// ---- strip of 8 weights, difference-form fast math (no catastrophic cancellation) ----------
__device__ __forceinline__ void side_weights(float tt, float e, float c, int sbase,
                                             float (&w)[8])
{
    float xprev = tt - (float)sbase * DS_F;
    float pa = 0.f;
    if (xprev > 0.f) pa = __builtin_amdgcn_exp2f(e * __builtin_amdgcn_logf(xprev));
    #pragma unroll
    for (int k = 1; k <= 8; ++k) {
        float xk = tt - (float)(sbase + k) * DS_F;
        float D, pan;
        if (xk > 0.f) {
            float om = xk * __builtin_amdgcn_rcpf(xprev);     // x_{k+1}/x_k in (0,1)
            float y2 = e * __builtin_amdgcn_logf(om);         // e*log2(om) <= 0
            float wl = y2 * LN2_F;                            // e*ln(om)
            float em = wl * (1.f + wl * (0.5f + wl * (0.16666667f + wl * (0.041666668f + wl * 0.008333334f))));
            float g = -em;
            if (wl < -0.3f) g = 1.f - __builtin_amdgcn_exp2f(y2);
            D = pa * g;
            pan = pa - D;
        } else {
            D = pa;
            pan = 0.f;
        }
        w[k - 1] = __builtin_amdgcn_sqrtf(D + 1e-12f) * c;
        pa = pan;
        xprev = xk;
    }
}

__device__ __forceinline__ unsigned pack_hl(float v)
{
    _Float16 h = (_Float16)v;
    _Float16 l = (_Float16)(v - (float)h);
    unsigned short hu = __builtin_bit_cast(unsigned short, h);
    unsigned short lu = __builtin_bit_cast(unsigned short, l);
    return (unsigned)hu | ((unsigned)lu << 16);
}

// ---------------- kmat_t: K(t) SORTED rows -> fp16 hi/lo split, [d][t_sorted][s] -----------
__global__ __launch_bounds__(256) void kmat_t_kernel(const float* __restrict__ tsort,
                                                     const int* __restrict__ perm,
                                                     const float4* __restrict__ coef,
                                                     _Float16* __restrict__ KThi,
                                                     _Float16* __restrict__ KTlo)
{
    int band = blockIdx.x >> 2;
    float bmax = tsort[band * 128 + 127];
    if ((float)(blockIdx.y * 64) * DS_F > bmax + DT_F + 0.07f) return;  // block-uniform
    int tid = threadIdx.x;
    int txx = tid & 31, sidx = tid >> 5;
    int t = blockIdx.x * 32 + txx;
    int sbase = blockIdx.y * 64 + sidx * 8;
    int d = blockIdx.z;
    __shared__ unsigned shhl[32][65];
    float tq = tsort[t];
    float4 cf = coef[(size_t)perm[t] * DIMN + d];
    float wa[8], wb[8];
    side_weights(tq,        cf.x, cf.y, sbase, wa);
    side_weights(tq + DT_F, cf.z, cf.w, sbase, wb);
    #pragma unroll
    for (int k = 0; k < 8; ++k) {
        float v = fmaxf(wb[k] - wa[k], 0.f) * SCALE_F;
        shhl[txx][sidx * 8 + k] = pack_hl(v);
    }
    __syncthreads();
    int tl = tid >> 3, sc = tid & 7;
    unsigned dwv[8];
    #pragma unroll
    for (int j = 0; j < 8; ++j) dwv[j] = shhl[tl][sc * 8 + j];
    uint4 hv, lv;
    hv.x = __builtin_amdgcn_perm(dwv[1], dwv[0], 0x05040100u);
    hv.y = __builtin_amdgcn_perm(dwv[3], dwv[2], 0x05040100u);
    hv.z = __builtin_amdgcn_perm(dwv[5], dwv[4], 0x05040100u);
    hv.w = __builtin_amdgcn_perm(dwv[7], dwv[6], 0x05040100u);
    lv.x = __builtin_amdgcn_perm(dwv[1], dwv[0], 0x07060302u);
    lv.y = __builtin_amdgcn_perm(dwv[3], dwv[2], 0x07060302u);
    lv.z = __builtin_amdgcn_perm(dwv[5], dwv[4], 0x07060302u);
    lv.w = __builtin_amdgcn_perm(dwv[7], dwv[6], 0x07060302u);
    size_t o = ((size_t)(d * 1024) + blockIdx.x * 32 + tl) * 2048 + blockIdx.y * 64 + sc * 8;
    *(uint4*)&KThi[o] = hv;
    *(uint4*)&KTlo[o] = lv;
}

// ---------------- kmat_z: fp32 [d][s][m] AND fp16 split transposed [d][m][s] ---------------
__global__ __launch_bounds__(256) void kmat_z_kernel(const float* __restrict__ times,
                                                     const float4* __restrict__ coef,
                                                     float* __restrict__ Kz,
                                                     _Float16* __restrict__ KzThi,
                                                     _Float16* __restrict__ KzTlo)
{
    int tid = threadIdx.x;
    int txx = tid & 31, sidx = tid >> 5;
    int m = blockIdx.x * 32 + txx;
    int sbase = blockIdx.y * 64 + sidx * 8;
    int d = blockIdx.z;
    __shared__ unsigned shhl[32][65];
    float tq = times[m];
    float4 cf = coef[(size_t)m * DIMN + d];
    float wa[8], wb[8];
    side_weights(tq,        cf.x, cf.y, sbase, wa);
    side_weights(tq + DT_F, cf.z, cf.w, sbase, wb);
    #pragma unroll
    for (int k = 0; k < 8; ++k) {
        float v = fmaxf(wb[k] - wa[k], 0.f) * SCALE_F;
        Kz[((size_t)d * SSTEPS + sbase + k) * 64 + m] = v;
        shhl[txx][sidx * 8 + k] = pack_hl(v);
    }
    __syncthreads();
    int tl = tid >> 3, sc = tid & 7;
    unsigned dwv[8];
    #pragma unroll
    for (int j = 0; j < 8; ++j) dwv[j] = shhl[tl][sc * 8 + j];
    uint4 hv, lv;
    hv.x = __builtin_amdgcn_perm(dwv[1], dwv[0], 0x05040100u);
    hv.y = __builtin_amdgcn_perm(dwv[3], dwv[2], 0x05040100u);
    hv.z = __builtin_amdgcn_perm(dwv[5], dwv[4], 0x05040100u);
    hv.w = __builtin_amdgcn_perm(dwv[7], dwv[6], 0x05040100u);
    lv.x = __builtin_amdgcn_perm(dwv[1], dwv[0], 0x07060302u);
    lv.y = __builtin_amdgcn_perm(dwv[3], dwv[2], 0x07060302u);
    lv.z = __builtin_amdgcn_perm(dwv[5], dwv[4], 0x07060302u);
    lv.w = __builtin_amdgcn_perm(dwv[7], dwv[6], 0x07060302u);
    size_t o = ((size_t)(d * 64) + blockIdx.x * 32 + tl) * 2048 + blockIdx.y * 64 + sc * 8;
    *(uint4*)&KzThi[o] = hv;
    *(uint4*)&KzTlo[o] = lv;
}

// ---------------- Kzz partials: Kz^T Kz per dim, k-split 8 ---------------------------------
__global__ __launch_bounds__(256) void kzz_partial_kernel(const float* __restrict__ Kz,
                                                          float* __restrict__ part)
{
    int kidx = blockIdx.x;           // 0..7 (256 s each)
    int d = blockIdx.y;
    int tid = threadIdx.x, tx = tid & 15, ty = tid >> 4;
    __shared__ float As[32][64];
    float acc[4][4] = {};
    const float* base = Kz + ((size_t)d * SSTEPS + (size_t)kidx * 256) * 64;
    for (int c = 0; c < 8; ++c) {
        __syncthreads();
        #pragma unroll
        for (int l = 0; l < 2; ++l) {
            int idx = tid + l * 256;               // 512 float4
            int r = idx >> 4, c4 = idx & 15;
            *(float4*)&As[r][c4 * 4] = *(const float4*)(base + (size_t)(c * 32 + r) * 64 + c4 * 4);
        }
        __syncthreads();
        #pragma unroll
        for (int k = 0; k < 32; ++k) {
            float av[4], bv[4];
            *(float4*)&av[0] = *(float4*)&As[k][ty * 4];
            *(float4*)&bv[0] = *(float4*)&As[k][tx * 4];
            #pragma unroll
            for (int i = 0; i < 4; ++i)
                #pragma unroll
                for (int j = 0; j < 4; ++j) acc[i][j] += av[i] * bv[j];
        }
    }
    float* dst = part + (size_t)(kidx * DIMN + d) * 4096;
    #pragma unroll
    for (int i = 0; i < 4; ++i)
        *(float4*)&dst[(size_t)(ty * 4 + i) * 64 + tx * 4] =
            make_float4(acc[i][0], acc[i][1], acc[i][2], acc[i][3]);
}

// ---------------- k-split reduce (Kzz only) ------------------------------------------------
__global__ void reduce_kernel(const float* __restrict__ in, float* __restrict__ out,
                              int n, int parts)
{
    int i = blockIdx.x * 256 + threadIdx.x;
    if (i >= n) return;
    float s = 0.f;
    for (int p = 0; p < parts; ++p) s += in[(size_t)p * n + i];
    out[i] = s;
}

// ---------------- Cholesky: crosslane rank-1, rows in VGPRs, zero-LDS hot loop -------------
// R18: chol was 72.8 us at 0.3% occupancy (serial LDS dot-products + barriers). Rewrite:
// thread i holds row i in registers (fully unrolled, static indices). Right-looking
// factorization: pivot broadcast + rank-1 update via compile-time-lane __shfl (v_readlane)
// -> no LDS reads, no barriers in the 64-pivot loop (single wave, lockstep, in-order).
// L stashed into the dead A staging tile for a coalesced epilogue; dBz accumulated on the fly.
__global__ __launch_bounds__(64) void chol_kernel(const float* __restrict__ Kzz,
                                                  const float* __restrict__ eps_z,
                                                  float* __restrict__ Lz, float* __restrict__ dBz)
{
    int d = blockIdx.x, i = threadIdx.x;
    __shared__ float A[64][65];
    for (int r = 0; r < 64; ++r)
        A[r][i] = Kzz[(size_t)d * 4096 + (size_t)r * 64 + i] + ((r == i) ? 1e-6f : 0.f);
    __syncthreads();
    float a[64];
    #pragma unroll
    for (int k = 0; k < 64; ++k) a[k] = A[i][k];   // row i -> VGPRs (2-way bank alias, free)
    float veps = eps_z[d * 64 + i];
    float db = 0.f;
    #pragma unroll
    for (int j = 0; j < 64; ++j) {
        float dsq = __shfl(a[j], j);               // lane j's A^(j)[j][j]
        float dj = sqrtf(fmaxf(dsq, 1e-30f));
        float l = (i >= j) ? (a[j] / dj) : 0.f;    // L[i][j]; i==j gives dj
        A[i][j] = l;                               // stash L (lane-owned row slot)
        db += l * __shfl(veps, j);                 // dB accumulates L[i][j]*eps[j]
        #pragma unroll
        for (int k = j + 1; k < 64; ++k)
            a[k] -= l * __shfl(l, k);              // rank-1: L[k][j] by readlane
    }
    __syncthreads();
    for (int r = 0; r < 64; ++r)
        Lz[(size_t)d * 4096 + (size_t)r * 64 + i] = (i <= r) ? A[r][i] : 0.f;
    dBz[d * 64 + i] = db;
}

// ---------------- Ktz partials via MFMA; sorted-t support clamp ----------------------------
__global__ __launch_bounds__(256, 2) void ktz_mfma_kernel(const _Float16* __restrict__ KThi,
                                                          const _Float16* __restrict__ KTlo,
                                                          const _Float16* __restrict__ KzThi,
                                                          const _Float16* __restrict__ KzTlo,
                                                          const float* __restrict__ tsort,
                                                          float* __restrict__ part)
{
    int tid = threadIdx.x;
    int wave = tid >> 6, lane = tid & 63;
    int n = lane & 15, q = lane >> 4;
    int lr = lane >> 2, lc = (lane & 3) * 8;
    int d = blockIdx.x;                 // fastest -> XCD locality
    int t0 = blockIdx.y * 128;
    int split = blockIdx.z;
    int wr = (wave >> 1) * 64, wc = (wave & 1) * 32;

    float tmax = tsort[t0 + 127];
    int klim = (int)floorf((tmax + DT_F) * 64.f) + 2;   // global 32-step chunk limit
    int nc = klim - split * 16;
    nc = nc < 0 ? 0 : (nc > 16 ? 16 : nc);

    __shared__ _Float16 Ah[2][128][32], Al[2][128][32];
    __shared__ _Float16 Bh[2][64][32],  Bl[2][64][32];   // 48 KB

    f32x4 acc[4][2];
    #pragma unroll
    for (int i = 0; i < 4; ++i)
        #pragma unroll
        for (int j = 0; j < 2; ++j) acc[i][j] = (f32x4)0.f;

    const size_t aRow = (size_t)(d * 1024 + t0);
    const size_t bRow = (size_t)(d * 64);
    int segA = wave * 32;               // 32 A rows per wave (2 instrs)
    int segB = wave * 16;               // 16 B rows per wave (1 instr)

    auto stage = [&](int buf, int c) {
        int s0 = split * 512 + c * 32;
        size_t ga = (aRow + segA + lr) * 2048 + s0 + lc;
        size_t gb = (bRow + segB + lr) * 2048 + s0 + lc;
        gl_lds16(KThi + ga,               &Ah[buf][segA][0]);
        gl_lds16(KThi + ga + 16 * 2048,   &Ah[buf][segA + 16][0]);
        gl_lds16(KTlo + ga,               &Al[buf][segA][0]);
        gl_lds16(KTlo + ga + 16 * 2048,   &Al[buf][segA + 16][0]);
        gl_lds16(KzThi + gb,              &Bh[buf][segB][0]);
        gl_lds16(KzTlo + gb,              &Bl[buf][segB][0]);
    };

    if (nc > 0) stage(0, 0);            // 6 DMA per wave
    for (int c = 0; c < nc; ++c) {
        int buf = c & 1;
        asm volatile("s_waitcnt vmcnt(0)" ::: "memory");
        __builtin_amdgcn_s_barrier();
        __builtin_amdgcn_sched_barrier(0);
        if (c + 1 < nc) stage(buf ^ 1, c + 1);   // overwrites buf read at c-1: drained
        f16x8 fAh[4], fAl[4], fBh[2], fBl[2];
        #pragma unroll
        for (int i = 0; i < 4; ++i) {
            fAh[i] = *(f16x8*)&Ah[buf][wr + i * 16 + n][q * 8];
            fAl[i] = *(f16x8*)&Al[buf][wr + i * 16 + n][q * 8];
        }
        #pragma unroll
        for (int j = 0; j < 2; ++j) {
            fBh[j] = *(f16x8*)&Bh[buf][wc + j * 16 + n][q * 8];
            fBl[j] = *(f16x8*)&Bl[buf][wc + j * 16 + n][q * 8];
        }
        __builtin_amdgcn_s_setprio(1);
        #pragma unroll
        for (int i = 0; i < 4; ++i)
            #pragma unroll
            for (int j = 0; j < 2; ++j) {
                acc[i][j] = __builtin_amdgcn_mfma_f32_16x16x32_f16(fAh[i], fBh[j], acc[i][j], 0, 0, 0);
                acc[i][j] = __builtin_amdgcn_mfma_f32_16x16x32_f16(fAh[i], fBl[j], acc[i][j], 0, 0, 0);
                acc[i][j] = __builtin_amdgcn_mfma_f32_16x16x32_f16(fAl[i], fBh[j], acc[i][j], 0, 0, 0);
            }
        __builtin_amdgcn_s_setprio(0);
    }
    float* dst = part + ((size_t)(split * DIMN + d)) * 1024 * 64;
    #pragma unroll
    for (int i = 0; i < 4; ++i)
        #pragma unroll
        for (int j = 0; j < 2; ++j)
            #pragma unroll
            for (int r = 0; r < 4; ++r) {
                int t = t0 + wr + i * 16 + q * 4 + r;
                dst[(size_t)t * 64 + wc + j * 16 + n] = acc[i][j][r];
            }
}

// ------ fused: sum Ktz partials + cho_solve + alpha splits + mean (perm-scattered) ---------
// R16-validated: B column staged through LDS (bLs[i][r], coalesced) then x[k] = bLs[k][i]
// -> register-resident solve with float4-broadcast L/LT rows.
__global__ __launch_bounds__(64) void solve_kernel(const float* __restrict__ Lz,
                                                   const float* __restrict__ part2,
                                                   const float* __restrict__ dBz,
                                                   const int* __restrict__ perm,
                                                   _Float16* __restrict__ aPhi,
                                                   _Float16* __restrict__ aPlo,
                                                   _Float16* __restrict__ aNhi,
                                                   _Float16* __restrict__ aNlo,
                                                   float* __restrict__ out0)
{
    int d = blockIdx.y;
    int t0 = blockIdx.x * 64;
    int i = threadIdx.x;
    __shared__ float L[64][68];       // row-major, padded: float4 at k%4==0 is 16B-aligned
    __shared__ float LT[64][68];      // LT[j][k] = L[k][j] for backward pass
    __shared__ float bLs[64][65];     // transpose staging: bLs[m][c] = B[t0+c][m]
    __shared__ float inv[64];
    __shared__ float dB[64];
    for (int r = 0; r < 64; ++r) {
        float v = Lz[(size_t)d * 4096 + (size_t)r * 64 + i];
        L[r][i] = v;
        LT[i][r] = v;
    }
    dB[i] = dBz[d * 64 + i];
    // coalesced global load (lane = m), transposed into LDS: bLs[i][r] = B[t0+r][m=i]
    for (int r = 0; r < 64; ++r) {
        size_t base = ((size_t)d * 1024 + t0 + r) * 64 + i;
        bLs[i][r] = (part2[base] + part2[base + 524288]) +
                    (part2[base + 1048576] + part2[base + 1572864]);
    }
    __syncthreads();
    inv[i] = 1.f / L[i][i];
    __syncthreads();
    // thread i's RHS column: x[k] = B[t0+i][m=k]  (row-k read, lane-stride-1, conflict-free)
    float x[64];
    #pragma unroll
    for (int k = 0; k < 64; ++k) x[k] = bLs[k][i];
    // forward: x[j] = (x[j] - sum_{k<j} L[j][k] x[k]) / L[j][j]; L rows via float4 broadcast
    #pragma unroll
    for (int j = 0; j < 64; ++j) {
        float s0 = 0.f, s1 = 0.f, s2 = 0.f, s3 = 0.f;
        #pragma unroll
        for (int k = 0; k + 4 <= j; k += 4) {
            float4 lv = *(const float4*)&L[j][k];
            s0 += lv.x * x[k];     s1 += lv.y * x[k + 1];
            s2 += lv.z * x[k + 2]; s3 += lv.w * x[k + 3];
        }
        #pragma unroll
        for (int k = j & ~3; k < j; ++k) s0 += L[j][k] * x[k];
        x[j] = (x[j] - ((s0 + s1) + (s2 + s3))) * inv[j];
    }
    // backward: x[j] = (x[j] - sum_{k>j} L[k][j] x[k]) / L[j][j]; LT rows via float4
    #pragma unroll
    for (int j = 63; j >= 0; --j) {
        float s0 = 0.f, s1 = 0.f, s2 = 0.f, s3 = 0.f;
        #pragma unroll
        for (int k = j + 1; k < ((j + 4) & ~3); ++k) s0 += LT[j][k] * x[k];   // head
        #pragma unroll
        for (int k = (j + 4) & ~3; k + 4 <= 64; k += 4) {
            float4 lv = *(const float4*)&LT[j][k];
            s0 += lv.x * x[k];     s1 += lv.y * x[k + 1];
            s2 += lv.z * x[k + 2]; s3 += lv.w * x[k + 3];
        }
        x[j] = (x[j] - ((s0 + s1) + (s2 + s3))) * inv[j];
    }
    // mean = dot(x, dB) -> scatter to ORIGINAL t index
    {
        float m0 = 0.f, m1 = 0.f, m2 = 0.f, m3 = 0.f;
        #pragma unroll
        for (int m = 0; m < 64; m += 4) {
            m0 += x[m]     * dB[m];
            m1 += x[m + 1] * dB[m + 1];
            m2 += x[m + 2] * dB[m + 2];
            m3 += x[m + 3] * dB[m + 3];
        }
        out0[d * 1024 + perm[t0 + i]] = (m0 + m1) + (m2 + m3);
    }
    // emit fp16 hi/lo splits, [d][t_sorted][m], +/- variants (all static indices)
    size_t o = ((size_t)(d * 1024 + t0 + i)) * 64;
    #pragma unroll
    for (int g = 0; g < 8; ++g) {
        union { _Float16 h[8]; float4 v; } ph, pl, nh, nl;
        #pragma unroll
        for (int k = 0; k < 8; ++k) {
            float xv = x[g * 8 + k];
            _Float16 h = (_Float16)xv;
            _Float16 lo = (_Float16)(xv - (float)h);
            ph.h[k] = h;  pl.h[k] = lo;
            nh.h[k] = -h; nl.h[k] = -lo;
        }
        *(float4*)&aPhi[o + g * 8] = ph.v;
        *(float4*)&aPlo[o + g * 8] = pl.v;
        *(float4*)&aNhi[o + g * 8] = nh.v;
        *(float4*)&aNlo[o + g * 8] = nl.v;
    }
}

// ---------------- var/std via MFMA: R7 structure + sorted-support chunk clamp --------------
__global__ __launch_bounds__(256, 3) void var_mfma_kernel(const _Float16* __restrict__ KThi,
                                                          const _Float16* __restrict__ KTlo,
                                                          const _Float16* __restrict__ aPhi,
                                                          const _Float16* __restrict__ aPlo,
                                                          const _Float16* __restrict__ aNhi,
                                                          const _Float16* __restrict__ aNlo,
                                                          const float* __restrict__ tsort,
                                                          const int* __restrict__ perm,
                                                          float* __restrict__ out1)
{
    int tid = threadIdx.x;
    int wave = tid >> 6, lane = tid & 63;
    int n = lane & 15, q = lane >> 4;
    int lr = lane >> 2;
    int lcs = (((lane & 3) ^ ((lr >> 1) & 3)) * 8);   // swizzled DMA source col (f16 units)
    int qs  = ((q ^ ((n >> 1) & 3)) * 8);             // swizzled LDS read col (f16 units)
    int d = blockIdx.x;                               // fastest -> XCD locality
    // decode triangle tile: per t-band ti (128 rows), u-tiles uj in [2*ti, 16)
    int ti = 0, rem = blockIdx.y;
    while (rem >= 16 - 2 * ti) { rem -= 16 - 2 * ti; ++ti; }
    int uj = 2 * ti + rem;
    int t0 = ti * 128, u0 = uj * 64;
    int wr = (wave >> 1) * 64, wc = (wave & 1) * 32;  // wave's 64(t) x 32(u) quadrant

    float tmaxv = tsort[t0 + 127];
    float umaxv = tsort[u0 + 63];
    int nck = (int)floorf((fminf(tmaxv, umaxv) + DT_F) * 64.f) + 2;
    if (nck > 64) nck = 64;
    int nit = nck + 2;                                // + alpha chunks {64,65}

    __shared__ _Float16 Ah[2][128][32], Al[2][128][32];   // 16 KB each
    __shared__ _Float16 Bh[2][64][32],  Bl[2][64][32];    // 8 KB each -> 48 KB total

    f32x4 acc[4][2];
    #pragma unroll
    for (int i = 0; i < 4; ++i)
        #pragma unroll
        for (int j = 0; j < 2; ++j) acc[i][j] = (f32x4)0.f;

    const size_t aRow = (size_t)(d * 1024 + t0);
    const size_t bRow = (size_t)(d * 1024 + u0);
    int sa = wave * 32;                 // A rows staged by this wave (2 instrs/plane)
    int sb = wave * 16;                 // B rows staged by this wave (1 instr/plane)

    auto stage = [&](int buf, int ck) {
        const _Float16 *ph, *pl, *qh, *ql;
        size_t str; int col;
        if (ck < 64) { ph = KThi; pl = KTlo; qh = KThi; ql = KTlo; str = 2048; col = ck * 32; }
        else         { ph = aPhi; pl = aPlo; qh = aNhi; ql = aNlo; str = 64;  col = (ck - 64) * 32; }
        size_t ga = (aRow + sa + lr) * str + col + lcs;
        size_t gb = (bRow + sb + lr) * str + col + lcs;
        gl_lds16(ph + ga,            &Ah[buf][sa][0]);
        gl_lds16(ph + ga + 16 * str, &Ah[buf][sa + 16][0]);
        gl_lds16(pl + ga,            &Al[buf][sa][0]);
        gl_lds16(pl + ga + 16 * str, &Al[buf][sa + 16][0]);
        gl_lds16(qh + gb,            &Bh[buf][sb][0]);
        gl_lds16(ql + gb,            &Bl[buf][sb][0]);
    };

    stage(0, 0);                         // 6 DMA per wave (nck >= 5 always: t >= 0.05)
    for (int it = 0; it < nit; ++it) {
        int buf = it & 1;
        asm volatile("s_waitcnt vmcnt(0)" ::: "memory");
        __builtin_amdgcn_s_barrier();
        __builtin_amdgcn_sched_barrier(0);
        int nx = it + 1;
        if (nx < nit) stage(buf ^ 1, nx < nck ? nx : 64 + (nx - nck));
        f16x8 fAh[4], fAl[4], fBh[2], fBl[2];
        #pragma unroll
        for (int i = 0; i < 4; ++i) {
            fAh[i] = *(f16x8*)&Ah[buf][wr + i * 16 + n][qs];
            fAl[i] = *(f16x8*)&Al[buf][wr + i * 16 + n][qs];
        }
        #pragma unroll
        for (int j = 0; j < 2; ++j) {
            fBh[j] = *(f16x8*)&Bh[buf][wc + j * 16 + n][qs];
            fBl[j] = *(f16x8*)&Bl[buf][wc + j * 16 + n][qs];
        }
        __builtin_amdgcn_s_setprio(1);
        #pragma unroll
        for (int i = 0; i < 4; ++i)
            #pragma unroll
            for (int j = 0; j < 2; ++j) {
                acc[i][j] = __builtin_amdgcn_mfma_f32_16x16x32_f16(fAh[i], fBh[j], acc[i][j], 0, 0, 0);
                acc[i][j] = __builtin_amdgcn_mfma_f32_16x16x32_f16(fAh[i], fBl[j], acc[i][j], 0, 0, 0);
                acc[i][j] = __builtin_amdgcn_mfma_f32_16x16x32_f16(fAl[i], fBh[j], acc[i][j], 0, 0, 0);
            }
        __builtin_amdgcn_s_setprio(0);
    }
    float* dst = out1 + ((size_t)d << 20);
    int tw0 = t0 + wr;                       // wave's first sorted t
    int uw0 = u0 + wc;                       // wave's first sorted u
    bool above = (uw0 >= tw0 + 64);          // whole wave strictly u > t (sorted idx)
    bool below = (uw0 + 32 <= tw0);          // whole wave strictly u < t (mirror elsewhere)
    if (!below) {
        #pragma unroll
        for (int i = 0; i < 4; ++i) {
            int tb = tw0 + i * 16 + q * 4;   // sorted t base for r=0..3
            #pragma unroll
            for (int j = 0; j < 2; ++j) {
                int u = uw0 + j * 16 + n;
                int pu = perm[u];
                float fv[4];
                #pragma unroll
                for (int r = 0; r < 4; ++r)
                    fv[r] = sqrtf(fmaxf(acc[i][j][r], 1e-12f)) * SQRTDT_F;
                if (above) {
                    #pragma unroll
                    for (int r = 0; r < 4; ++r)
                        dst[(size_t)perm[tb + r] * 1024 + u] = fv[r];
                    // mirror: final row pu, sorted cols tb..tb+3 contiguous -> coalesced
                    *(float4*)&dst[(size_t)pu * 1024 + tb] = make_float4(fv[0], fv[1], fv[2], fv[3]);
                } else {
                    #pragma unroll
                    for (int r = 0; r < 4; ++r) {
                        int t = tb + r;
                        if (u >= t) dst[(size_t)perm[t] * 1024 + u] = fv[r];
                        if (u > t)  dst[(size_t)pu * 1024 + t] = fv[r];
                    }
                }
            }
        }
    }
}

// ---------------- in-place column un-permutation of out1 (rows already final) --------------
__global__ __launch_bounds__(256) void colperm_kernel(float* __restrict__ out1,
                                                      const int* __restrict__ invp)
{
    int d = blockIdx.y, row = blockIdx.x;
    float* rp = out1 + ((size_t)d << 20) + (size_t)row * 1024;
    __shared__ float buf[1024];
    int tid = threadIdx.x;
    *(float4*)&buf[tid * 4] = *(float4*)&rp[tid * 4];
    __syncthreads();
    #pragma unroll
    for (int k = 0; k < 4; ++k) {
        int b = tid + k * 256;
        rp[b] = buf[invp[b]];
    }
}

extern "C" void kernel_launch(void* const* d_in, const int* in_sizes, int n_in,
                              void* d_out, int out_size, void* d_ws, size_t ws_size,
                              hipStream_t stream)
{
    const float* t_in  = (const float*)d_in[0];
    const float* y0    = (const float*)d_in[1];
    const float* eps_z = (const float*)d_in[2];
    const float* W1    = (const float*)d_in[3];
    const float* b1    = (const float*)d_in[4];
    const float* W2    = (const float*)d_in[5];
    const float* b2    = (const float*)d_in[6];
    const float* Wc1   = (const float*)d_in[7];
    const float* bc1   = (const float*)d_in[8];
    const float* Wc2   = (const float*)d_in[9];
    const float* bc2   = (const float*)d_in[10];
    const float* dw    = (const float*)d_in[11];
    const float* cw    = (const float*)d_in[12];

    float* ws = (float*)d_ws;
    size_t off = 0;
    auto carve = [&](size_t n) { float* p = ws + off; off += n; return p; };
    float* coef_t   = carve(32768);
    float* coef_z   = carve(2048);
    float* times_z  = carve(64);
    float* Kzz      = carve(32768);
    float* Lz       = carve(32768);
    float* dBz      = carve(512);
    float* Kz       = carve(1048576);
    _Float16* KThi  = (_Float16*)carve(8388608);
    _Float16* KTlo  = (_Float16*)carve(8388608);
    _Float16* KzThi = (_Float16*)carve(524288);
    _Float16* KzTlo = (_Float16*)carve(524288);
    float* part1    = carve(262144);
    float* part2    = carve(2097152);
    _Float16* aPhi  = (_Float16*)carve(262144);
    _Float16* aPlo  = (_Float16*)carve(262144);
    _Float16* aNhi  = (_Float16*)carve(262144);
    _Float16* aNlo  = (_Float16*)carve(262144);
    float* tsort    = carve(1024);
    int*   perm_i   = (int*)carve(1024);
    int*   inv_i    = (int*)carve(1024);

    float* out0 = (float*)d_out;
    float* out1 = out0 + (size_t)DIMN * 1024;

    coef_kernel<<<9, 128, 0, stream>>>(t_in, y0, W1, b1, W2, b2, Wc1, bc1, Wc2, bc2, dw, cw,
                                       (float4*)coef_t, (float4*)coef_z, times_z);
    sort_kernel<<<1, 512, 0, stream>>>(t_in, tsort, perm_i, inv_i);
    kmat_t_kernel<<<dim3(32, 32, 8), 256, 0, stream>>>(tsort, perm_i, (const float4*)coef_t,
                                                       KThi, KTlo);
    kmat_z_kernel<<<dim3(2, 32, 8), 256, 0, stream>>>(times_z, (const float4*)coef_z,
                                                      Kz, KzThi, KzTlo);
    kzz_partial_kernel<<<dim3(8, 8), 256, 0, stream>>>(Kz, part1);
    reduce_kernel<<<128, 256, 0, stream>>>(part1, Kzz, 32768, 8);
    chol_kernel<<<8, 64, 0, stream>>>(Kzz, eps_z, Lz, dBz);
    ktz_mfma_kernel<<<dim3(8, 8, 4), 256, 0, stream>>>(KThi, KTlo, KzThi, KzTlo, tsort, part2);
    solve_kernel<<<dim3(16, 8), 64, 0, stream>>>(Lz, part2, dBz, perm_i,
                                                 aPhi, aPlo, aNhi, aNlo, out0);
    var_mfma_kernel<<<dim3(8, 72), 256, 0, stream>>>(KThi, KTlo, aPhi, aPlo, aNhi, aNlo,
                                                     tsort, perm_i, out1);
    colperm_kernel<<<dim3(1024, 8), 256, 0, stream>>>(out1, inv_i);
}